// Round 4
// baseline (194.378 us; speedup 1.0000x reference)
//
#include <hip/hip_runtime.h>
#include <cstddef>

#define LL 100
#define DD 64
#define NG 4   // groups (waves) per 256-thread block

typedef float vf4 __attribute__((ext_vector_type(4)));

// x += dpp_move(x, CTRL); bound_ctrl=true, full masks.
template<int CTRL>
__device__ __forceinline__ float dpp_add(float x) {
    int s = __builtin_amdgcn_update_dpp(0, __float_as_int(x), CTRL, 0xF, 0xF, true);
    return x + __int_as_float(s);
}

// Butterfly sum within each 16-lane group; result broadcast to ALL 16 lanes.
__device__ __forceinline__ float sum16_all(float x) {
    x = dpp_add<0xB1>(x);   // quad_perm [1,0,3,2]
    x = dpp_add<0x4E>(x);   // quad_perm [2,3,0,1]
    x = dpp_add<0x141>(x);  // row_half_mirror
    x = dpp_add<0x140>(x);  // row_mirror
    return x;
}

// Nontemporal 16B load (native ext_vector_type — HIP_vector_type is rejected).
__device__ __forceinline__ vf4 nt_load4(const float* p) {
    return __builtin_nontemporal_load((const vf4*)p);
}

// attn = softmax_l( <seqs[l,:], W2·p> ) — V_last/V_avg/b are per-group logit
// constants, cancelled by softmax => W1/W3/b/lens drop out.
//
// Round-13: phase-coherence fix + instrumentation.
// Ledger: cold reads pin at 2.2 TB/s across {opcode, return path, depth
// 5/10/15 KB}; warm re-read of same addrs = 8.5 TB/s (r12); fills fully
// drain in their own window (6.8 TB/s). Remaining hypothesis: decoupled
// wave-streams scatter the in-flight request window over 105 MB => DRAM
// row/queue thrash (fast streamers — fills, grid-stride copies, GEMM
// K-loops — all have dense or barrier-coupled windows).
// Fix: RAW s_barrier per 5-pack batch (NOT __syncthreads — that drains
// vmcnt(0) and would kill the 15-deep prefetch). Couples the block's waves.
// Diagnostics kept this round: sweep A (warm, same addrs — anchor, +12.4us
// known) and sweep B (remote group +2048 — L3-residency probe) to push the
// kernel above the 61us fills so its FETCH/VALUBusy surface in top-5.
__global__ __launch_bounds__(256, 4) void seq_encoder_fused(
    const float* __restrict__ seqs,
    const float* __restrict__ W2,  const float* __restrict__ p,
    const float* __restrict__ Wq,  const float* __restrict__ Wl0,
    const float* __restrict__ bl0, const float* __restrict__ Wl1,
    const float* __restrict__ bl1, float* __restrict__ out)
{
    __shared__ __align__(16) float s_q2[DD];
    __shared__ __align__(16) float s_w[NG][DD];        // pooled vectors
    __shared__ __align__(16) float s_p[2][NG][2 * DD]; // MLP k-split partials
    __shared__ __align__(16) float s_h0[NG][2 * DD];
    __shared__ __align__(16) float s_h1[NG][2 * DD];

    const int tid = threadIdx.x;
    const int r = tid >> 6;      // wave id = group within block
    const int lane = tid & 63;

    // ---- q2 = W2 · p, cooperative across the block (W2 is L2-resident) ----
    {
        const int row = tid >> 2, part = tid & 3;
        const float* wrow = W2 + row * DD + part * 16;
        const float* pp = p + part * 16;
        float s = 0.f;
        #pragma unroll
        for (int e = 0; e < 16; ++e) s += wrow[e] * pp[e];
        s += __shfl_down(s, 2);
        s += __shfl_down(s, 1);
        if (part == 0) s_q2[row] = s;
    }
    __syncthreads();

    // lane layout over a 4-row pack: rg = row in pack, cb = 4-column block
    const int rg = lane >> 4;
    const int cb = lane & 15;
    const float4 q2v = *(const float4*)&s_q2[cb * 4];

    const int gi = blockIdx.x * NG + r;
    const float* Sp = seqs + (size_t)gi * (LL * DD) + (rg * 16 + cb) * 4;

    float z = 0.f;                                  // sum of exp (own row-group rows)
    float wx = 0.f, wy = 0.f, wzv = 0.f, ww = 0.f;  // pooling acc

    // ---- attention: 25 packs = 5 batches of 5, QUAD-buffered (lookahead 3),
    //      per-batch raw s_barrier keeps the block's waves phase-locked ----
    vf4 buf[4][5];
    #pragma unroll
    for (int j = 0; j < 5; ++j) buf[0][j] = nt_load4(Sp + j * 256);
    #pragma unroll
    for (int j = 0; j < 5; ++j) buf[1][j] = nt_load4(Sp + (5 + j) * 256);
    #pragma unroll
    for (int j = 0; j < 5; ++j) buf[2][j] = nt_load4(Sp + (10 + j) * 256);

    #pragma unroll
    for (int b = 0; b < 5; ++b) {
        if (b > 0) __builtin_amdgcn_s_barrier();   // phase-lock, NO vmcnt drain
        if (b + 3 < 5) {
            #pragma unroll
            for (int j = 0; j < 5; ++j)
                buf[(b + 3) % 4][j] = nt_load4(Sp + ((b + 3) * 5 + j) * 256);
        }
        #pragma unroll
        for (int j = 0; j < 5; ++j) {
            vf4 x = buf[b % 4][j];
            float t = x.x * q2v.x + x.y * q2v.y + x.z * q2v.z + x.w * q2v.w;
            t = sum16_all(t);     // this lane's row logit, broadcast in 16-group
            float e = __expf(t);
            z += e;
            wx  += e * x.x; wy += e * x.y;
            wzv += e * x.z; ww += e * x.w;
        }
    }

    // ---- DIAGNOSTIC SWEEP A (this round only): warm re-read, same addrs.
    // Anchor: measured +12.4us in r12. Laundered pointer defeats CSE. ----
    {
        const float* SpA = Sp;
        asm volatile("" : "+v"(SpA));
        float a0 = 0.f, a1 = 0.f, a2 = 0.f, a3 = 0.f;
        #pragma unroll
        for (int j = 0; j < 25; ++j) {
            vf4 x = nt_load4(SpA + j * 256);
            a0 += x.x; a1 += x.y; a2 += x.z; a3 += x.w;
        }
        asm volatile("" :: "v"(a0), "v"(a1), "v"(a2), "v"(a3));
    }
    // ---- DIAGNOSTIC SWEEP B (this round only): remote group (+2048).
    // L3-residency probe for nt-fetched lines: ~+12us if L3-served,
    // ~+45us if HBM re-fetch. ----
    {
        const int gi2 = (gi + 2048) & 4095;
        const float* SpB = seqs + (size_t)gi2 * (LL * DD) + (rg * 16 + cb) * 4;
        asm volatile("" : "+v"(SpB));
        float a0 = 0.f, a1 = 0.f, a2 = 0.f, a3 = 0.f;
        #pragma unroll
        for (int j = 0; j < 25; ++j) {
            vf4 x = nt_load4(SpB + j * 256);
            a0 += x.x; a1 += x.y; a2 += x.z; a3 += x.w;
        }
        asm volatile("" :: "v"(a0), "v"(a1), "v"(a2), "v"(a3));
    }

    // merge the 4 row-groups
    z   += __shfl_xor(z, 16);   z   += __shfl_xor(z, 32);
    wx  += __shfl_xor(wx, 16);  wx  += __shfl_xor(wx, 32);
    wy  += __shfl_xor(wy, 16);  wy  += __shfl_xor(wy, 32);
    wzv += __shfl_xor(wzv, 16); wzv += __shfl_xor(wzv, 32);
    ww  += __shfl_xor(ww, 16);  ww  += __shfl_xor(ww, 32);

    const float invz = 1.f / z;
    if (rg == 0) {
        float4 o;
        o.x = wx * invz; o.y = wy * invz; o.z = wzv * invz; o.w = ww * invz;
        *(float4*)&s_w[r][cb * 4] = o;
    }
    __syncthreads();

    // ---- MLP, 2-way k-split: each weight element read ONCE per block ----
    const int jt = tid & 127;
    const int hf = tid >> 7;
    const int g0 = 2 * hf;

    // Stage 1: h0 = s_w @ Wq   (64x128; halves cover k=0..31 / 32..63)
    {
        float p0 = 0.f, p1 = 0.f, p2 = 0.f, p3 = 0.f;
        const int k0 = hf * 32;
        for (int k = k0; k < k0 + 32; ++k) {
            float wv = Wq[k * (2 * DD) + jt];
            p0 += s_w[0][k] * wv; p1 += s_w[1][k] * wv;
            p2 += s_w[2][k] * wv; p3 += s_w[3][k] * wv;
        }
        s_p[hf][0][jt] = p0; s_p[hf][1][jt] = p1;
        s_p[hf][2][jt] = p2; s_p[hf][3][jt] = p3;
    }
    __syncthreads();
    {
        s_h0[g0][jt]     = s_p[0][g0][jt]     + s_p[1][g0][jt];
        s_h0[g0 + 1][jt] = s_p[0][g0 + 1][jt] + s_p[1][g0 + 1][jt];
    }
    __syncthreads();

    // Stage 2: h1 = relu(h0 @ Wl0 + bl0)  (128x128; halves cover k=0..63 / 64..127)
    {
        float p0 = 0.f, p1 = 0.f, p2 = 0.f, p3 = 0.f;
        const int k0 = hf * 64;
        for (int k = k0; k < k0 + 64; ++k) {
            float wv = Wl0[k * (2 * DD) + jt];
            p0 += s_h0[0][k] * wv; p1 += s_h0[1][k] * wv;
            p2 += s_h0[2][k] * wv; p3 += s_h0[3][k] * wv;
        }
        s_p[hf][0][jt] = p0; s_p[hf][1][jt] = p1;
        s_p[hf][2][jt] = p2; s_p[hf][3][jt] = p3;
    }
    __syncthreads();
    {
        float bv = bl0[jt];
        s_h1[g0][jt]     = fmaxf(s_p[0][g0][jt]     + s_p[1][g0][jt]     + bv, 0.f);
        s_h1[g0 + 1][jt] = fmaxf(s_p[0][g0 + 1][jt] + s_p[1][g0 + 1][jt] + bv, 0.f);
    }
    __syncthreads();

    // Stage 3: out = h0 + relu(h1 @ Wl1 + bl1)
    {
        float p0 = 0.f, p1 = 0.f, p2 = 0.f, p3 = 0.f;
        const int k0 = hf * 64;
        for (int k = k0; k < k0 + 64; ++k) {
            float wv = Wl1[k * (2 * DD) + jt];
            p0 += s_h1[0][k] * wv; p1 += s_h1[1][k] * wv;
            p2 += s_h1[2][k] * wv; p3 += s_h1[3][k] * wv;
        }
        s_p[hf][0][jt] = p0; s_p[hf][1][jt] = p1;
        s_p[hf][2][jt] = p2; s_p[hf][3][jt] = p3;
    }
    __syncthreads();
    {
        float bv = bl1[jt];
        float oa = fmaxf(s_p[0][g0][jt]     + s_p[1][g0][jt]     + bv, 0.f);
        float ob = fmaxf(s_p[0][g0 + 1][jt] + s_p[1][g0 + 1][jt] + bv, 0.f);
        const size_t gbase = (size_t)blockIdx.x * NG;
        out[(gbase + g0) * (2 * DD) + jt]     = s_h0[g0][jt]     + oa;
        out[(gbase + g0 + 1) * (2 * DD) + jt] = s_h0[g0 + 1][jt] + ob;
    }
}

extern "C" void kernel_launch(void* const* d_in, const int* in_sizes, int n_in,
                              void* d_out, int out_size, void* d_ws, size_t ws_size,
                              hipStream_t stream) {
    const float* seqs = (const float*)d_in[0];
    // d_in[1] = lens, d_in[2] = W1, d_in[4] = W3, d_in[5] = b : cancel in softmax
    const float* W2   = (const float*)d_in[3];
    const float* p    = (const float*)d_in[6];
    const float* Wq   = (const float*)d_in[7];
    const float* Wl0  = (const float*)d_in[8];
    const float* bl0  = (const float*)d_in[9];
    const float* Wl1  = (const float*)d_in[10];
    const float* bl1  = (const float*)d_in[11];
    float* out = (float*)d_out;

    const int n_groups = 64 * 64;  // BS * G
    seq_encoder_fused<<<n_groups / NG, 256, 0, stream>>>(
        seqs, W2, p, Wq, Wl0, bl0, Wl1, bl1, out);
}

// Round 5
// 171.282 us; speedup vs baseline: 1.1348x; 1.1348x over previous
//
#include <hip/hip_runtime.h>
#include <cstddef>

#define LL 100
#define DD 64
#define NG 4   // groups (waves) per 256-thread block

typedef float vf4 __attribute__((ext_vector_type(4)));

// x += dpp_move(x, CTRL); bound_ctrl=true, full masks.
template<int CTRL>
__device__ __forceinline__ float dpp_add(float x) {
    int s = __builtin_amdgcn_update_dpp(0, __float_as_int(x), CTRL, 0xF, 0xF, true);
    return x + __int_as_float(s);
}

// Butterfly sum within each 16-lane group; result broadcast to ALL 16 lanes.
__device__ __forceinline__ float sum16_all(float x) {
    x = dpp_add<0xB1>(x);   // quad_perm [1,0,3,2]
    x = dpp_add<0x4E>(x);   // quad_perm [2,3,0,1]
    x = dpp_add<0x141>(x);  // row_half_mirror
    x = dpp_add<0x140>(x);  // row_mirror
    return x;
}

// Nontemporal 16B load (native ext_vector_type — HIP_vector_type is rejected).
__device__ __forceinline__ vf4 nt_load4(const float* p) {
    return __builtin_nontemporal_load((const vf4*)p);
}

// attn = softmax_l( <seqs[l,:], W2·p> ) — V_last/V_avg/b are per-group logit
// constants, cancelled by softmax => W1/W3/b/lens drop out.
//
// Round-14: DENSE-FRONT test (hypothesis H2). Ledger: cold 2.14 TB/s across
// {opcode, return path, depth 5/10/15 KB, block barriers}; warm re-read
// 8.5 TB/s (r12); remote-group re-read ALSO warm (r13: +11us) => lines
// allocate in MALL/L2 despite nt. Untried structural variable: the in-flight
// front is 4096 independent wave-streams (1 KB islands, 25.6 KB spacing).
// Fix: pack-interleave the block's 100 packs across its 4 waves (t = 4j+r),
// phase-locked by per-batch raw s_barrier (proven free, r13) => each block
// streams one contiguous 102 KB region with a dense 40 KB in-flight window
// (matches the 6.8 TB/s fill's front shape). Each wave keeps 4 per-group
// partial (z, pooled) accumulator sets (compile-time selected after full
// unroll; 3 straddle iters use a uniform branchless mask), merged via a 4 KB
// LDS reduction. Traffic unchanged; VGPR ~110; occupancy 4 blocks/CU.
// Predict: H2 => dur 171 -> 150-156. Null => 169-173, then test MALL-bypass
// (nt|sc1 inline-asm loads) vs drain-hypothesis H1, else declare roofline.
__global__ __launch_bounds__(256, 4) void seq_encoder_fused(
    const float* __restrict__ seqs,
    const float* __restrict__ W2,  const float* __restrict__ p,
    const float* __restrict__ Wq,  const float* __restrict__ Wl0,
    const float* __restrict__ bl0, const float* __restrict__ Wl1,
    const float* __restrict__ bl1, float* __restrict__ out)
{
    __shared__ __align__(16) float s_q2[DD];
    __shared__ __align__(16) float s_zpart[NG][NG];      // [wave][group]
    __shared__ __align__(16) float s_wpart[NG][NG][DD];  // [wave][group][dim]
    __shared__ __align__(16) float s_w[NG][DD];          // pooled vectors
    __shared__ __align__(16) float s_p[2][NG][2 * DD];   // MLP k-split partials
    __shared__ __align__(16) float s_h0[NG][2 * DD];
    __shared__ __align__(16) float s_h1[NG][2 * DD];

    const int tid = threadIdx.x;
    const int r = tid >> 6;      // wave id
    const int lane = tid & 63;

    // ---- q2 = W2 · p, cooperative across the block (W2 is L2-resident) ----
    {
        const int row = tid >> 2, part = tid & 3;
        const float* wrow = W2 + row * DD + part * 16;
        const float* pp = p + part * 16;
        float s = 0.f;
        #pragma unroll
        for (int e = 0; e < 16; ++e) s += wrow[e] * pp[e];
        s += __shfl_down(s, 2);
        s += __shfl_down(s, 1);
        if (part == 0) s_q2[row] = s;
    }
    __syncthreads();

    // lane layout over a 4-row pack: rg = row in pack, cb = 4-column block
    const int rg = lane >> 4;
    const int cb = lane & 15;
    const float4 q2v = *(const float4*)&s_q2[cb * 4];

    // Block streams its CONTIGUOUS 4-group region; wave r takes packs t=4j+r.
    const float* Sp = seqs + (size_t)blockIdx.x * (NG * LL * DD) + r * 256 + lane * 4;

    float z[NG]  = {0.f, 0.f, 0.f, 0.f};   // per-group sum of exp (partial)
    vf4   acc[NG];                          // per-group pooled accum (partial)
    #pragma unroll
    for (int g = 0; g < NG; ++g) acc[g] = (vf4){0.f, 0.f, 0.f, 0.f};

    // ---- 25 iters = 5 batches of 5, triple-buffered (lookahead 2 batches =
    //      10 KB/wave, 40 KB dense window/block), s_barrier phase-lock ----
    vf4 buf[3][5];
    #pragma unroll
    for (int jj = 0; jj < 5; ++jj) buf[0][jj] = nt_load4(Sp + jj * 1024);
    #pragma unroll
    for (int jj = 0; jj < 5; ++jj) buf[1][jj] = nt_load4(Sp + (5 + jj) * 1024);

    #pragma unroll
    for (int b = 0; b < 5; ++b) {
        if (b > 0) __builtin_amdgcn_s_barrier();   // phase-lock, NO vmcnt drain
        if (b + 2 < 5) {
            #pragma unroll
            for (int jj = 0; jj < 5; ++jj)
                buf[(b + 2) % 3][jj] = nt_load4(Sp + ((b + 2) * 5 + jj) * 1024);
        }
        #pragma unroll
        for (int jj = 0; jj < 5; ++jj) {
            const int j   = b * 5 + jj;       // compile-time after unroll
            const int t0  = 4 * j;            // pack index of wave 0 this iter
            const int glo = t0 / 25;          // group of wave 0's pack
            const int ghi = (t0 + 3) / 25;    // group of wave 3's pack

            vf4 x = buf[b % 3][jj];
            float t = x.x * q2v.x + x.y * q2v.y + x.z * q2v.z + x.w * q2v.w;
            t = sum16_all(t);                 // row logit, broadcast in 16-group
            float e = __expf(t);

            if (glo == ghi) {                 // 22 of 25 iters: uniform group
                z[glo] += e;
                acc[glo].x += e * x.x; acc[glo].y += e * x.y;
                acc[glo].z += e * x.z; acc[glo].w += e * x.w;
            } else {                          // straddle (j = 6, 12, 18)
                const float ehi = (r >= (25 * ghi - t0)) ? e : 0.f; // wave-uniform
                const float elo = e - ehi;
                z[glo] += elo; z[ghi] += ehi;
                acc[glo].x += elo * x.x; acc[glo].y += elo * x.y;
                acc[glo].z += elo * x.z; acc[glo].w += elo * x.w;
                acc[ghi].x += ehi * x.x; acc[ghi].y += ehi * x.y;
                acc[ghi].z += ehi * x.z; acc[ghi].w += ehi * x.w;
            }
        }
    }

    // merge the 4 row-groups within the wave, per accumulator set
    #pragma unroll
    for (int g = 0; g < NG; ++g) {
        z[g]     += __shfl_xor(z[g], 16);     z[g]     += __shfl_xor(z[g], 32);
        acc[g].x += __shfl_xor(acc[g].x, 16); acc[g].x += __shfl_xor(acc[g].x, 32);
        acc[g].y += __shfl_xor(acc[g].y, 16); acc[g].y += __shfl_xor(acc[g].y, 32);
        acc[g].z += __shfl_xor(acc[g].z, 16); acc[g].z += __shfl_xor(acc[g].z, 32);
        acc[g].w += __shfl_xor(acc[g].w, 16); acc[g].w += __shfl_xor(acc[g].w, 32);
    }
    if (rg == 0) {
        #pragma unroll
        for (int g = 0; g < NG; ++g) {
            *(vf4*)&s_wpart[r][g][cb * 4] = acc[g];
            if (cb == 0) s_zpart[r][g] = z[g];
        }
    }
    __syncthreads();

    // wave r finalizes group r: sum 4 wave-partials, normalize
    if (rg == 0) {
        float zz = s_zpart[0][r] + s_zpart[1][r] + s_zpart[2][r] + s_zpart[3][r];
        const float invz = 1.f / zz;
        vf4 a = *(const vf4*)&s_wpart[0][r][cb * 4];
        vf4 a1 = *(const vf4*)&s_wpart[1][r][cb * 4];
        vf4 a2 = *(const vf4*)&s_wpart[2][r][cb * 4];
        vf4 a3 = *(const vf4*)&s_wpart[3][r][cb * 4];
        a.x = (a.x + a1.x + a2.x + a3.x) * invz;
        a.y = (a.y + a1.y + a2.y + a3.y) * invz;
        a.z = (a.z + a1.z + a2.z + a3.z) * invz;
        a.w = (a.w + a1.w + a2.w + a3.w) * invz;
        *(vf4*)&s_w[r][cb * 4] = a;
    }
    __syncthreads();

    // ---- MLP, 2-way k-split: each weight element read ONCE per block ----
    const int jt = tid & 127;
    const int hf = tid >> 7;
    const int g0 = 2 * hf;

    // Stage 1: h0 = s_w @ Wq   (64x128; halves cover k=0..31 / 32..63)
    {
        float p0 = 0.f, p1 = 0.f, p2 = 0.f, p3 = 0.f;
        const int k0 = hf * 32;
        for (int k = k0; k < k0 + 32; ++k) {
            float wv = Wq[k * (2 * DD) + jt];
            p0 += s_w[0][k] * wv; p1 += s_w[1][k] * wv;
            p2 += s_w[2][k] * wv; p3 += s_w[3][k] * wv;
        }
        s_p[hf][0][jt] = p0; s_p[hf][1][jt] = p1;
        s_p[hf][2][jt] = p2; s_p[hf][3][jt] = p3;
    }
    __syncthreads();
    {
        s_h0[g0][jt]     = s_p[0][g0][jt]     + s_p[1][g0][jt];
        s_h0[g0 + 1][jt] = s_p[0][g0 + 1][jt] + s_p[1][g0 + 1][jt];
    }
    __syncthreads();

    // Stage 2: h1 = relu(h0 @ Wl0 + bl0)  (128x128; halves cover k=0..63 / 64..127)
    {
        float p0 = 0.f, p1 = 0.f, p2 = 0.f, p3 = 0.f;
        const int k0 = hf * 64;
        for (int k = k0; k < k0 + 64; ++k) {
            float wv = Wl0[k * (2 * DD) + jt];
            p0 += s_h0[0][k] * wv; p1 += s_h0[1][k] * wv;
            p2 += s_h0[2][k] * wv; p3 += s_h0[3][k] * wv;
        }
        s_p[hf][0][jt] = p0; s_p[hf][1][jt] = p1;
        s_p[hf][2][jt] = p2; s_p[hf][3][jt] = p3;
    }
    __syncthreads();
    {
        float bv = bl0[jt];
        s_h1[g0][jt]     = fmaxf(s_p[0][g0][jt]     + s_p[1][g0][jt]     + bv, 0.f);
        s_h1[g0 + 1][jt] = fmaxf(s_p[0][g0 + 1][jt] + s_p[1][g0 + 1][jt] + bv, 0.f);
    }
    __syncthreads();

    // Stage 3: out = h0 + relu(h1 @ Wl1 + bl1)
    {
        float p0 = 0.f, p1 = 0.f, p2 = 0.f, p3 = 0.f;
        const int k0 = hf * 64;
        for (int k = k0; k < k0 + 64; ++k) {
            float wv = Wl1[k * (2 * DD) + jt];
            p0 += s_h1[0][k] * wv; p1 += s_h1[1][k] * wv;
            p2 += s_h1[2][k] * wv; p3 += s_h1[3][k] * wv;
        }
        s_p[hf][0][jt] = p0; s_p[hf][1][jt] = p1;
        s_p[hf][2][jt] = p2; s_p[hf][3][jt] = p3;
    }
    __syncthreads();
    {
        float bv = bl1[jt];
        float oa = fmaxf(s_p[0][g0][jt]     + s_p[1][g0][jt]     + bv, 0.f);
        float ob = fmaxf(s_p[0][g0 + 1][jt] + s_p[1][g0 + 1][jt] + bv, 0.f);
        const size_t gbase = (size_t)blockIdx.x * NG;
        out[(gbase + g0) * (2 * DD) + jt]     = s_h0[g0][jt]     + oa;
        out[(gbase + g0 + 1) * (2 * DD) + jt] = s_h0[g0 + 1][jt] + ob;
    }
}

extern "C" void kernel_launch(void* const* d_in, const int* in_sizes, int n_in,
                              void* d_out, int out_size, void* d_ws, size_t ws_size,
                              hipStream_t stream) {
    const float* seqs = (const float*)d_in[0];
    // d_in[1] = lens, d_in[2] = W1, d_in[4] = W3, d_in[5] = b : cancel in softmax
    const float* W2   = (const float*)d_in[3];
    const float* p    = (const float*)d_in[6];
    const float* Wq   = (const float*)d_in[7];
    const float* Wl0  = (const float*)d_in[8];
    const float* bl0  = (const float*)d_in[9];
    const float* Wl1  = (const float*)d_in[10];
    const float* bl1  = (const float*)d_in[11];
    float* out = (float*)d_out;

    const int n_groups = 64 * 64;  // BS * G
    seq_encoder_fused<<<n_groups / NG, 256, 0, stream>>>(
        seqs, W2, p, Wq, Wl0, bl0, Wl1, bl1, out);
}